// Round 1
// baseline (8346.917 us; speedup 1.0000x reference)
//
#include <hip/hip_runtime.h>
#include <math.h>

#define Bn   32
#define Tn   256
#define DIN  768
#define DHn  512
#define DEn  25
#define Cn   9
#define K3   2304   // 3*DIN
#define H3   1536   // 3*DH
#define NCOL 3072   // 2*H3
#define MROW 8192   // B*T

// ---------------- gi pre-GEMM: gi[m][n] = lmr[m][:] . W[n][:] + bih[n] ----------------
#define BM 128
#define BN 128
#define BK 16

__global__ __launch_bounds__(256) void gi_gemm_kernel(
    const float* __restrict__ X, const float* __restrict__ pad,
    const float* __restrict__ Wf, const float* __restrict__ Wb,
    const float* __restrict__ bf, const float* __restrict__ bb,
    float* __restrict__ gi)
{
  __shared__ __align__(16) float As[BK][BM + 4];
  __shared__ __align__(16) float Bs[BK][BN + 4];
  const int bm = blockIdx.x, bn = blockIdx.y;
  const int tid = threadIdx.x;
  const int tx = tid & 15, ty = tid >> 4;
  const int m0 = bm * BM, n0 = bn * BN;
  // whole 128-col tile lies in one direction's Wih (1536 % 128 == 0)
  const bool isF = (n0 < H3);
  const float* Wmat = isF ? Wf : Wb;
  const float* bias = isF ? bf : bb;
  const int nbase = isF ? n0 : (n0 - H3);

  float acc[8][8];
#pragma unroll
  for (int i = 0; i < 8; i++)
#pragma unroll
    for (int j = 0; j < 8; j++) acc[i][j] = 0.f;

  const int lrow = tid >> 2;       // 0..63
  const int lk = (tid & 3) * 4;    // 0,4,8,12

  for (int k0 = 0; k0 < K3; k0 += BK) {
    // ---- stage A tile (virtual lmr: trigram window over padded X) ----
#pragma unroll
    for (int i = 0; i < 2; i++) {
      int row = lrow + i * 64;
      int m = m0 + row;
      int b = m >> 8, t = m & 255;
      int kg = k0 + lk;
      int seg = (kg >= DIN) + (kg >= 2 * DIN);
      int off = kg - seg * DIN;
      int p = t + seg;                       // position in X_pad: 0..257
      float4 v;
      if (p == 0 || p == Tn + 1) v = *reinterpret_cast<const float4*>(pad + off);
      else v = *reinterpret_cast<const float4*>(X + (size_t)(b * Tn + (p - 1)) * DIN + off);
      As[lk + 0][row] = v.x; As[lk + 1][row] = v.y;
      As[lk + 2][row] = v.z; As[lk + 3][row] = v.w;
    }
    // ---- stage B tile (rows of Wih) ----
#pragma unroll
    for (int i = 0; i < 2; i++) {
      int row = lrow + i * 64;
      const float* wp = Wmat + (size_t)(nbase + row) * K3 + k0 + lk;
      float4 v = *reinterpret_cast<const float4*>(wp);
      Bs[lk + 0][row] = v.x; Bs[lk + 1][row] = v.y;
      Bs[lk + 2][row] = v.z; Bs[lk + 3][row] = v.w;
    }
    __syncthreads();
#pragma unroll
    for (int kk = 0; kk < BK; kk++) {
      float4 a0 = *reinterpret_cast<const float4*>(&As[kk][ty * 8]);
      float4 a1 = *reinterpret_cast<const float4*>(&As[kk][ty * 8 + 4]);
      float4 b0 = *reinterpret_cast<const float4*>(&Bs[kk][tx * 8]);
      float4 b1 = *reinterpret_cast<const float4*>(&Bs[kk][tx * 8 + 4]);
      float av[8] = {a0.x, a0.y, a0.z, a0.w, a1.x, a1.y, a1.z, a1.w};
      float bv[8] = {b0.x, b0.y, b0.z, b0.w, b1.x, b1.y, b1.z, b1.w};
#pragma unroll
      for (int i = 0; i < 8; i++)
#pragma unroll
        for (int j = 0; j < 8; j++)
          acc[i][j] = fmaf(av[i], bv[j], acc[i][j]);
    }
    __syncthreads();
  }
  // ---- epilogue: + bih, store ----
#pragma unroll
  for (int i = 0; i < 8; i++) {
    int m = m0 + ty * 8 + i;
    float* orow = gi + (size_t)m * NCOL + n0 + tx * 8;
    float4 o0, o1;
    o0.x = acc[i][0] + bias[nbase + tx * 8 + 0];
    o0.y = acc[i][1] + bias[nbase + tx * 8 + 1];
    o0.z = acc[i][2] + bias[nbase + tx * 8 + 2];
    o0.w = acc[i][3] + bias[nbase + tx * 8 + 3];
    o1.x = acc[i][4] + bias[nbase + tx * 8 + 4];
    o1.y = acc[i][5] + bias[nbase + tx * 8 + 5];
    o1.z = acc[i][6] + bias[nbase + tx * 8 + 6];
    o1.w = acc[i][7] + bias[nbase + tx * 8 + 7];
    *reinterpret_cast<float4*>(orow) = o0;
    *reinterpret_cast<float4*>(orow + 4) = o1;
  }
}

// ---------------- Whh transpose to [dir][K/4][1536][4] for coalesced streaming ----------------
__global__ __launch_bounds__(256) void whh_transpose_kernel(
    const float* __restrict__ Wf, const float* __restrict__ Wb, float* __restrict__ Wt)
{
  int idx = blockIdx.x * 256 + threadIdx.x;
  if (idx >= 2 * H3 * DHn) return;
  int d = idx / (H3 * DHn);
  int r = (idx / DHn) % H3;
  int k = idx % DHn;
  const float* W = d ? Wb : Wf;
  float v = W[(size_t)r * DHn + k];
  Wt[(size_t)d * (DHn / 4) * H3 * 4 + (size_t)(k >> 2) * (H3 * 4) + r * 4 + (k & 3)] = v;
}

// ---------------- GRU recurrence: one WG per (batch, dir) ----------------
__global__ __launch_bounds__(512) void gru_rec_kernel(
    const float* __restrict__ gi,     // [8192][3072]
    const float* __restrict__ Wt,     // [2][128][1536][4]
    const float* __restrict__ bhh_f, const float* __restrict__ bhh_b,
    float* __restrict__ out)          // [B][T][1024]
{
  __shared__ __align__(16) float h[DHn];
  const int w = blockIdx.x;          // 0..63
  const int x = w & 7;               // XCD steering: dir f -> XCD 0-3, dir b -> 4-7
  const int dir = (x >= 4) ? 1 : 0;
  const int b = (w >> 3) * 4 + (x & 3);
  const float* bhh = dir ? bhh_b : bhh_f;
  const float* wt = Wt + (size_t)dir * (DHn / 4) * H3 * 4;
  const int u = threadIdx.x;         // 0..511

  h[u] = 0.f;
  __syncthreads();

  const float brv = bhh[u], bzv = bhh[DHn + u], bnv = bhh[2 * DHn + u];

  for (int s = 0; s < Tn; s++) {
    const int t = dir ? (Tn - 1 - s) : s;
    const float* g = gi + (size_t)(b * Tn + t) * NCOL + dir * H3;
    float hr = brv, hz = bzv, hn = bnv;
#pragma unroll 4
    for (int k4 = 0; k4 < DHn / 4; k4++) {
      float4 hv = *reinterpret_cast<const float4*>(&h[k4 * 4]);           // LDS broadcast
      const float* base = wt + (size_t)k4 * (H3 * 4);
      float4 w1 = *reinterpret_cast<const float4*>(base + u * 4);         // r row
      float4 w2 = *reinterpret_cast<const float4*>(base + (DHn + u) * 4); // z row
      float4 w3 = *reinterpret_cast<const float4*>(base + (2 * DHn + u) * 4); // n row
      hr = fmaf(hv.x, w1.x, hr); hr = fmaf(hv.y, w1.y, hr);
      hr = fmaf(hv.z, w1.z, hr); hr = fmaf(hv.w, w1.w, hr);
      hz = fmaf(hv.x, w2.x, hz); hz = fmaf(hv.y, w2.y, hz);
      hz = fmaf(hv.z, w2.z, hz); hz = fmaf(hv.w, w2.w, hz);
      hn = fmaf(hv.x, w3.x, hn); hn = fmaf(hv.y, w3.y, hn);
      hn = fmaf(hv.z, w3.z, hn); hn = fmaf(hv.w, w3.w, hn);
    }
    float ir = g[u], iz = g[DHn + u], inn = g[2 * DHn + u];
    float r = 1.f / (1.f + expf(-(ir + hr)));
    float z = 1.f / (1.f + expf(-(iz + hz)));
    float n = tanhf(inn + r * hn);
    float hold = h[u];
    float hnew = (1.f - z) * n + z * hold;
    __syncthreads();                 // everyone done reading old h
    h[u] = hnew;
    out[(size_t)(b * Tn + t) * 1024 + dir * DHn + u] = hnew;
    __syncthreads();                 // h fully updated
  }
}

// ---------------- decoder: per-batch sequential argmax-feedback chain ----------------
__global__ __launch_bounds__(64) void decoder_kernel(
    const float* __restrict__ out_h,      // [B][T][1024] (already in d_out)
    const float* __restrict__ label_emb,  // [10][25]
    const float* __restrict__ Wc,         // [9][1049]
    const float* __restrict__ bc,         // [9]
    float* __restrict__ out_chunk)        // [B*T][9]
{
  __shared__ float wcs[Cn * 1049];
  __shared__ float embs[(Cn + 1) * DEn];
  const int b = blockIdx.x;
  const int lane = threadIdx.x;
  for (int i = lane; i < Cn * 1049; i += 64) wcs[i] = Wc[i];
  for (int i = lane; i < (Cn + 1) * DEn; i += 64) embs[i] = label_emb[i];
  float bcv[Cn];
#pragma unroll
  for (int c = 0; c < Cn; c++) bcv[c] = bc[c];
  __syncthreads();

  int prev = Cn;  // start token = last row of label_emb
  for (int t = 0; t < Tn; t++) {
    const float* ht = out_h + (size_t)(b * Tn + t) * 1024;
    float hreg[16];
#pragma unroll
    for (int i = 0; i < 16; i++) hreg[i] = ht[lane + 64 * i];
    float acc[Cn];
#pragma unroll
    for (int c = 0; c < Cn; c++) {
      const float* wrow = &wcs[c * 1049];
      float a = 0.f;
#pragma unroll
      for (int i = 0; i < 16; i++) a = fmaf(hreg[i], wrow[lane + 64 * i], a);
      if (lane < DEn) a = fmaf(embs[prev * DEn + lane], wrow[1024 + lane], a);
      acc[c] = a;
    }
#pragma unroll
    for (int off = 32; off; off >>= 1)
#pragma unroll
      for (int c = 0; c < Cn; c++) acc[c] += __shfl_xor(acc[c], off);
#pragma unroll
    for (int c = 0; c < Cn; c++) acc[c] += bcv[c];
    // argmax (first occurrence) + softmax, replicated on all lanes
    float mx = acc[0]; int idx = 0;
#pragma unroll
    for (int c = 1; c < Cn; c++) if (acc[c] > mx) { mx = acc[c]; idx = c; }
    float e[Cn]; float sum = 0.f;
#pragma unroll
    for (int c = 0; c < Cn; c++) { e[c] = expf(acc[c] - mx); sum += e[c]; }
    float inv = 1.f / sum;
    if (lane < Cn) out_chunk[(size_t)(b * Tn + t) * Cn + lane] = e[lane] * inv;
    prev = idx;
  }
}

extern "C" void kernel_launch(void* const* d_in, const int* in_sizes, int n_in,
                              void* d_out, int out_size, void* d_ws, size_t ws_size,
                              hipStream_t stream) {
  const float* X      = (const float*)d_in[0];
  const float* pad    = (const float*)d_in[1];
  const float* lemb   = (const float*)d_in[2];
  const float* Wih_f  = (const float*)d_in[3];
  const float* Whh_f  = (const float*)d_in[4];
  const float* bih_f  = (const float*)d_in[5];
  const float* bhh_f  = (const float*)d_in[6];
  const float* Wih_b  = (const float*)d_in[7];
  const float* Whh_b  = (const float*)d_in[8];
  const float* bih_b  = (const float*)d_in[9];
  const float* bhh_b  = (const float*)d_in[10];
  const float* Wc     = (const float*)d_in[11];
  const float* bc     = (const float*)d_in[12];
  float* out = (float*)d_out;

  float* gi = (float*)d_ws;                               // 8192*3072*4 = 100,663,296 B
  float* Wt = (float*)((char*)d_ws + (size_t)MROW * NCOL * 4);  // + 6,291,456 B

  whh_transpose_kernel<<<dim3((2 * H3 * DHn + 255) / 256), dim3(256), 0, stream>>>(Whh_f, Whh_b, Wt);
  gi_gemm_kernel<<<dim3(MROW / BM, NCOL / BN), dim3(256), 0, stream>>>(X, pad, Wih_f, Wih_b, bih_f, bih_b, gi);
  gru_rec_kernel<<<dim3(64), dim3(512), 0, stream>>>(gi, Wt, bhh_f, bhh_b, out);
  decoder_kernel<<<dim3(Bn), dim3(64), 0, stream>>>(out, lemb, Wc, bc, out + (size_t)MROW * 1024);
}